// Round 4
// baseline (517.593 us; speedup 1.0000x reference)
//
#include <hip/hip_runtime.h>
#include <hip/hip_bf16.h>

#define V_ 32000
#define E_ 512
#define H_ 512
#define B_ 32
#define T_ 48
#define NWG 16   // persistent workgroups in recurrence

typedef __attribute__((ext_vector_type(8))) short bf16x8;
typedef __attribute__((ext_vector_type(4))) float f32x4;
typedef __attribute__((ext_vector_type(4))) int   i32x4;
typedef __attribute__((ext_vector_type(2))) int   i32x2;

static __device__ __forceinline__ short f2bf(float f) {
  union { __hip_bfloat16 h; short s; } u;
  u.h = __float2bfloat16(f);
  return u.s;
}

// load 8 consecutive f32 (32B aligned) -> bf16x8 fragment
static __device__ __forceinline__ bf16x8 load_cvt8(const float* p) {
  float4 a = *(const float4*)p;
  float4 b = *(const float4*)(p + 4);
  bf16x8 r;
  r[0] = f2bf(a.x); r[1] = f2bf(a.y); r[2] = f2bf(a.z); r[3] = f2bf(a.w);
  r[4] = f2bf(b.x); r[5] = f2bf(b.y); r[6] = f2bf(b.z); r[7] = f2bf(b.w);
  return r;
}

static __device__ __forceinline__ float sigf(float x) {
  return 1.0f / (1.0f + __expf(-x));
}
static __device__ __forceinline__ float tanh_fast(float x) {
  float e = __expf(2.0f * x);
  return (e - 1.0f) / (e + 1.0f);
}

// 16 coherent (sc0 sc1) 16B loads at stride 64B from one base address.
// "=&v" early-clobber: outputs must NOT alias the address input (%16) --
// loads 2..16 still read the address after load 1 writes its dest.
#define HLOADS16(T, ADDR)                                              \
  asm volatile(                                                        \
    "global_load_dwordx4 %0,  %16, off sc0 sc1\n\t"                    \
    "global_load_dwordx4 %1,  %16, off offset:64 sc0 sc1\n\t"          \
    "global_load_dwordx4 %2,  %16, off offset:128 sc0 sc1\n\t"         \
    "global_load_dwordx4 %3,  %16, off offset:192 sc0 sc1\n\t"         \
    "global_load_dwordx4 %4,  %16, off offset:256 sc0 sc1\n\t"         \
    "global_load_dwordx4 %5,  %16, off offset:320 sc0 sc1\n\t"         \
    "global_load_dwordx4 %6,  %16, off offset:384 sc0 sc1\n\t"         \
    "global_load_dwordx4 %7,  %16, off offset:448 sc0 sc1\n\t"         \
    "global_load_dwordx4 %8,  %16, off offset:512 sc0 sc1\n\t"         \
    "global_load_dwordx4 %9,  %16, off offset:576 sc0 sc1\n\t"         \
    "global_load_dwordx4 %10, %16, off offset:640 sc0 sc1\n\t"         \
    "global_load_dwordx4 %11, %16, off offset:704 sc0 sc1\n\t"         \
    "global_load_dwordx4 %12, %16, off offset:768 sc0 sc1\n\t"         \
    "global_load_dwordx4 %13, %16, off offset:832 sc0 sc1\n\t"         \
    "global_load_dwordx4 %14, %16, off offset:896 sc0 sc1\n\t"         \
    "global_load_dwordx4 %15, %16, off offset:960 sc0 sc1"             \
    : "=&v"(T[0]),  "=&v"(T[1]),  "=&v"(T[2]),  "=&v"(T[3]),           \
      "=&v"(T[4]),  "=&v"(T[5]),  "=&v"(T[6]),  "=&v"(T[7]),           \
      "=&v"(T[8]),  "=&v"(T[9]),  "=&v"(T[10]), "=&v"(T[11]),          \
      "=&v"(T[12]), "=&v"(T[13]), "=&v"(T[14]), "=&v"(T[15])           \
    : "v"(ADDR) : "memory")

// ---------------------------------------------------------------------------
// Kernel 1: Xg[t][b][j] = x_t[b] @ W_ih^T [j] + b_ih[j] + b_hh[j]
// ---------------------------------------------------------------------------
__global__ __launch_bounds__(256) void k_xg(
    const float* __restrict__ img,   // [32][512]
    const int*   __restrict__ gt,    // [32][48]
    const float* __restrict__ emb,   // [32000][512]
    const float* __restrict__ W_ih,  // [2048][512]
    const float* __restrict__ b_ih,
    const float* __restrict__ b_hh,
    float* __restrict__ Xg)          // [48][32][2048]
{
  const int s    = blockIdx.x;
  const int lane = threadIdx.x & 63;
  const int wv   = threadIdx.x >> 6;
  const int nbase = blockIdx.y * 256 + wv * 64;
  const int lr  = lane & 15;
  const int lkb = lane >> 4;

  const float* arow[2];
#pragma unroll
  for (int m = 0; m < 2; ++m) {
    int b = m * 16 + lr;
    const float* src;
    if (s == 0) {
      src = img + b * E_;
    } else {
      int tok = (s == 1) ? 1 : gt[b * T_ + (s - 1)];
      src = emb + (long)tok * E_;
    }
    arow[m] = src;
  }

  f32x4 acc[2][4];
#pragma unroll
  for (int m = 0; m < 2; ++m)
#pragma unroll
    for (int n = 0; n < 4; ++n) acc[m][n] = (f32x4){0.f, 0.f, 0.f, 0.f};

  for (int kt = 0; kt < 16; ++kt) {
    int ko = kt * 32 + lkb * 8;
    bf16x8 a0 = load_cvt8(arow[0] + ko);
    bf16x8 a1 = load_cvt8(arow[1] + ko);
#pragma unroll
    for (int n = 0; n < 4; ++n) {
      const float* wp = W_ih + (long)(nbase + n * 16 + lr) * E_ + ko;
      bf16x8 bw = load_cvt8(wp);
      acc[0][n] = __builtin_amdgcn_mfma_f32_16x16x32_bf16(a0, bw, acc[0][n], 0, 0, 0);
      acc[1][n] = __builtin_amdgcn_mfma_f32_16x16x32_bf16(a1, bw, acc[1][n], 0, 0, 0);
    }
  }

#pragma unroll
  for (int n = 0; n < 4; ++n) {
    int j = nbase + n * 16 + lr;
    float bias = b_ih[j] + b_hh[j];
#pragma unroll
    for (int m = 0; m < 2; ++m) {
#pragma unroll
      for (int r = 0; r < 4; ++r) {
        int b = m * 16 + lkb * 4 + r;
        Xg[((long)(s * B_ + b) * 2048) + j] = acc[m][n][r] + bias;
      }
    }
  }
}

// ---------------------------------------------------------------------------
// Kernel 2: sequential LSTM recurrence. NWG=16 persistent WGs x 256 threads.
// WG w owns hidden dims [32w, 32w+32). Wave wv = gate wv. W_hh slice in LDS.
// Cross-WG h exchange via coherent sc0/sc1 loads+stores (no buffer_wbl2 /
// buffer_inv): store h write-through, vmcnt ack, RELAXED counter add,
// all-thread relaxed poll.
// ---------------------------------------------------------------------------
__global__ __launch_bounds__(256, 1) void k_lstm(
    const float* __restrict__ W_hh,      // [2048][512]
    const float* __restrict__ Xg,        // [48][32][2048]
    unsigned short* __restrict__ hbuf,   // [2][32][512] bf16 (double buffer)
    unsigned short* __restrict__ hs,     // [1504][512] bf16 output states
    unsigned int* __restrict__ cnt)      // barrier counter (zeroed)
{
  __shared__ __align__(16) char wlds[128 * 1024];   // A-frags for this WG
  __shared__ __align__(16) char gbufc[16 * 1024];   // gate exchange, xor-swizzled
  const int wgid = blockIdx.x;   // 0..15
  const int tid  = threadIdx.x;
  const int lane = tid & 63;
  const int wv   = tid >> 6;     // gate index 0..3 (i,f,g,o)
  const int lr   = lane & 15;
  const int lkb  = lane >> 4;

  // preload W_hh fragments into LDS: gate=wv, d-tiles 0..1, kt 0..15
#pragma unroll
  for (int tile = 0; tile < 2; ++tile) {
    int row = wv * 512 + wgid * 32 + tile * 16 + lr;
#pragma unroll
    for (int kt = 0; kt < 16; ++kt) {
      bf16x8 w = load_cvt8(W_hh + (long)row * E_ + kt * 32 + lkb * 8);
      *(bf16x8*)(wlds + ((((wv * 2 + tile) * 16 + kt) * 64) + lane) * 16) = w;
    }
  }

  // cell-state ownership: thread -> b = tid>>3, d0 = (tid&7)*4
  f32x4 cst = (f32x4){0.f, 0.f, 0.f, 0.f};
  const int cb_b  = tid >> 3;
  const int cb_d0 = (tid & 7) * 4;

  __syncthreads();

  for (int t = 0; t < 48; ++t) {
    const unsigned short* hcur = hbuf + (t & 1) * (B_ * H_);

    // Xg slice (normal loads, L2/L3-cached; overlap with h loads below)
    float4 xg[2][2];
#pragma unroll
    for (int tile = 0; tile < 2; ++tile)
#pragma unroll
      for (int nt = 0; nt < 2; ++nt) {
        int b = nt * 16 + lr;
        xg[tile][nt] = *(const float4*)(Xg + (long)(t * B_ + b) * 2048 +
                                        wv * 512 + wgid * 32 + tile * 16 + lkb * 4);
      }

    // B-fragments: coherent h loads (bypass stale L1/L2)
    i32x4 tA[16], tB[16];
    const char* aA = (const char*)hcur + (0 * 16 + lr) * 1024 + lkb * 16;
    const char* aB = (const char*)hcur + (1 * 16 + lr) * 1024 + lkb * 16;
    HLOADS16(tA, aA);
    HLOADS16(tB, aB);
    asm volatile("s_waitcnt vmcnt(0)" ::: "memory");
    __builtin_amdgcn_sched_barrier(0);

    f32x4 acc[2][2];
#pragma unroll
    for (int tile = 0; tile < 2; ++tile)
#pragma unroll
      for (int nt = 0; nt < 2; ++nt) acc[tile][nt] = (f32x4){0.f, 0.f, 0.f, 0.f};

#pragma unroll
    for (int kt = 0; kt < 16; ++kt) {
      bf16x8 a0 = *(const bf16x8*)(wlds + ((((wv * 2 + 0) * 16 + kt) * 64) + lane) * 16);
      bf16x8 a1 = *(const bf16x8*)(wlds + ((((wv * 2 + 1) * 16 + kt) * 64) + lane) * 16);
      bf16x8 b0 = *(const bf16x8*)&tA[kt];
      bf16x8 b1 = *(const bf16x8*)&tB[kt];
      acc[0][0] = __builtin_amdgcn_mfma_f32_16x16x32_bf16(a0, b0, acc[0][0], 0, 0, 0);
      acc[0][1] = __builtin_amdgcn_mfma_f32_16x16x32_bf16(a0, b1, acc[0][1], 0, 0, 0);
      acc[1][0] = __builtin_amdgcn_mfma_f32_16x16x32_bf16(a1, b0, acc[1][0], 0, 0, 0);
      acc[1][1] = __builtin_amdgcn_mfma_f32_16x16x32_bf16(a1, b1, acc[1][1], 0, 0, 0);
    }

    // D: col = b (lane&15), row = d local = lkb*4 + reg.  gbuf xor-swizzled.
#pragma unroll
    for (int tile = 0; tile < 2; ++tile)
#pragma unroll
      for (int nt = 0; nt < 2; ++nt) {
        int b = nt * 16 + lr;
        f32x4 r = acc[tile][nt];
        r[0] += xg[tile][nt].x; r[1] += xg[tile][nt].y;
        r[2] += xg[tile][nt].z; r[3] += xg[tile][nt].w;
        int byte = (wv * 32 + b) * 128 + (((tile * 16 + lkb * 4) * 4) ^ ((b & 7) << 4));
        *(f32x4*)(gbufc + byte) = r;
      }
    __syncthreads();

    // cell update: 4 cells per thread (b = cb_b, d = cb_d0..+3)
    int rb = ((cb_d0 * 4) ^ ((cb_b & 7) << 4));
    float4 gi  = *(const float4*)(gbufc + (0 * 32 + cb_b) * 128 + rb);
    float4 gf  = *(const float4*)(gbufc + (1 * 32 + cb_b) * 128 + rb);
    float4 gg_ = *(const float4*)(gbufc + (2 * 32 + cb_b) * 128 + rb);
    float4 go  = *(const float4*)(gbufc + (3 * 32 + cb_b) * 128 + rb);
    float iv[4] = {gi.x, gi.y, gi.z, gi.w};
    float fv[4] = {gf.x, gf.y, gf.z, gf.w};
    float gv[4] = {gg_.x, gg_.y, gg_.z, gg_.w};
    float ov[4] = {go.x, go.y, go.z, go.w};
    unsigned short hb[4];
#pragma unroll
    for (int r = 0; r < 4; ++r) {
      float i_ = sigf(iv[r]);
      float f_ = sigf(fv[r]);
      float g_ = tanh_fast(gv[r]);
      float o_ = sigf(ov[r]);
      float c_ = f_ * cst[r] + i_ * g_;
      cst[r] = c_;
      float hv = o_ * tanh_fast(c_);
      hb[r] = (unsigned short)f2bf(hv);
    }
    ushort4 pack = {hb[0], hb[1], hb[2], hb[3]};

    // hs store (normal; consumed by k_head after kernel boundary)
    if (t >= 1)
      *(ushort4*)(hs + ((long)(t - 1) * B_ + cb_b) * H_ + wgid * 32 + cb_d0) = pack;

    if (t < 47) {
      // coherent write-through h store + ack
      unsigned short* hn = hbuf + ((t + 1) & 1) * (B_ * H_) +
                           cb_b * H_ + wgid * 32 + cb_d0;
      i32x2 pk;
      pk[0] = (int)pack.x | ((int)pack.y << 16);
      pk[1] = (int)pack.z | ((int)pack.w << 16);
      asm volatile("global_store_dwordx2 %0, %1, off sc0 sc1\n\t"
                   "s_waitcnt vmcnt(0)"
                   :: "v"(hn), "v"(pk) : "memory");
      __syncthreads();   // all threads' stores acked at coherence point
      if (tid == 0)
        __hip_atomic_fetch_add(cnt, 1u, __ATOMIC_RELAXED, __HIP_MEMORY_SCOPE_AGENT);
      unsigned target = (unsigned)NWG * (unsigned)(t + 1);
      while (__hip_atomic_load(cnt, __ATOMIC_RELAXED, __HIP_MEMORY_SCOPE_AGENT) < target)
        __builtin_amdgcn_s_sleep(1);
    }
  }
}

// ---------------------------------------------------------------------------
// Kernel 3: logits = hs @ W_head^T + b_head -> out[s][b][v], s=1..47
// ---------------------------------------------------------------------------
__global__ __launch_bounds__(256) void k_head(
    const float* __restrict__ W_head,        // [32000][512]
    const float* __restrict__ b_head,        // [32000]
    const unsigned short* __restrict__ hs,   // [1504][512] bf16
    float* __restrict__ out)                 // [48][32][32000]
{
  __shared__ __align__(16) char alds[16 * 1024];
  const int lane = threadIdx.x & 63;
  const int wv   = threadIdx.x >> 6;
  const int v0   = blockIdx.x * 64 + wv * 16;
  const int lr   = lane & 15;
  const int lkb  = lane >> 4;

  bf16x8 bw[16];
#pragma unroll
  for (int kt = 0; kt < 16; ++kt)
    bw[kt] = load_cvt8(W_head + (long)(v0 + lr) * E_ + kt * 32 + lkb * 8);
  float bias = b_head[v0 + lr];

  for (int mt = 0; mt < 94; ++mt) {
    __syncthreads();
    const char* src = (const char*)(hs + (long)mt * 16 * H_);
#pragma unroll
    for (int i = 0; i < 4; ++i) {
      int c = i * 256 + threadIdx.x;   // 1024 x 16B chunks
      int row = c >> 6;
      int cb  = (c & 63) * 16;
      int4 val = *(const int4*)(src + c * 16);
      *(int4*)(alds + row * 1024 + (cb ^ ((row & 7) << 4))) = val;
    }
    __syncthreads();

    f32x4 acc = (f32x4){bias, bias, bias, bias};
#pragma unroll
    for (int kt = 0; kt < 16; ++kt) {
      int cb = kt * 64 + lkb * 16;
      int4 av = *(const int4*)(alds + lr * 1024 + (cb ^ ((lr & 7) << 4)));
      bf16x8 a = *(bf16x8*)&av;
      acc = __builtin_amdgcn_mfma_f32_16x16x32_bf16(a, bw[kt], acc, 0, 0, 0);
    }

#pragma unroll
    for (int r = 0; r < 4; ++r) {
      int R = mt * 16 + lkb * 4 + r;
      out[(long)(R + 32) * V_ + v0 + lr] = acc[r];
    }
  }
}

// ---------------------------------------------------------------------------
extern "C" void kernel_launch(void* const* d_in, const int* in_sizes, int n_in,
                              void* d_out, int out_size, void* d_ws, size_t ws_size,
                              hipStream_t stream) {
  const float* img  = (const float*)d_in[0];
  const int*   gt   = (const int*)d_in[1];
  const float* emb  = (const float*)d_in[2];
  const float* W_ih = (const float*)d_in[3];
  const float* W_hh = (const float*)d_in[4];
  const float* b_ih = (const float*)d_in[5];
  const float* b_hh = (const float*)d_in[6];
  const float* W_hd = (const float*)d_in[7];
  const float* b_hd = (const float*)d_in[8];
  float* out = (float*)d_out;

  char* ws = (char*)d_ws;
  unsigned int*   cnt  = (unsigned int*)(ws);                       // 256 B
  unsigned short* hbuf = (unsigned short*)(ws + 256);               // 65536 B
  unsigned short* hs   = (unsigned short*)(ws + 256 + 65536);       // 1540096 B
  float*          Xg   = (float*)(ws + 256 + 65536 + 1540096);      // 12582912 B

  hipMemsetAsync(cnt, 0, 256, stream);
  hipMemsetAsync(hbuf, 0, B_ * H_ * sizeof(unsigned short), stream);  // h_0 = 0
  hipMemsetAsync(out, 0, (size_t)B_ * V_ * sizeof(float), stream);    // outputs[0] = 0

  dim3 g1(48, 8);
  k_xg<<<g1, 256, 0, stream>>>(img, gt, emb, W_ih, b_ih, b_hh, Xg);
  k_lstm<<<NWG, 256, 0, stream>>>(W_hh, Xg, hbuf, hs, cnt);
  k_head<<<500, 256, 0, stream>>>(W_hd, b_hd, hs, out);
}

// Round 5
// 405.745 us; speedup vs baseline: 1.2757x; 1.2757x over previous
//
#include <hip/hip_runtime.h>
#include <hip/hip_bf16.h>

#define V_ 32000
#define E_ 512
#define H_ 512
#define B_ 32
#define T_ 48
#define NWG 32          // recurrence workgroups (blocks 0..31)
#define NCON 250        // head-consumer workgroups (blocks 32..281)
#define GRID (NWG + NCON)

typedef __attribute__((ext_vector_type(8))) short bf16x8;
typedef __attribute__((ext_vector_type(4))) float f32x4;
typedef __attribute__((ext_vector_type(4))) int   i32x4;

static __device__ __forceinline__ short f2bf(float f) {
  union { __hip_bfloat16 h; short s; } u;
  u.h = __float2bfloat16(f);
  return u.s;
}

static __device__ __forceinline__ bf16x8 load_cvt8(const float* p) {
  float4 a = *(const float4*)p;
  float4 b = *(const float4*)(p + 4);
  bf16x8 r;
  r[0] = f2bf(a.x); r[1] = f2bf(a.y); r[2] = f2bf(a.z); r[3] = f2bf(a.w);
  r[4] = f2bf(b.x); r[5] = f2bf(b.y); r[6] = f2bf(b.z); r[7] = f2bf(b.w);
  return r;
}

static __device__ __forceinline__ float sigf(float x) {
  return 1.0f / (1.0f + __expf(-x));
}
static __device__ __forceinline__ float tanh_fast(float x) {
  float e = __expf(2.0f * x);
  return (e - 1.0f) / (e + 1.0f);
}

// coherent (sc0 sc1) flag load, fully acked
static __device__ __forceinline__ unsigned prog_load(const unsigned* p) {
  unsigned v;
  asm volatile("global_load_dword %0, %1, off sc0 sc1\n\t"
               "s_waitcnt vmcnt(0)"
               : "=&v"(v) : "v"(p) : "memory");
  return v;
}

// 16 coherent 16B loads at stride 64B. "=&v": outputs must not alias address.
#define HLOADS16(T, ADDR)                                              \
  asm volatile(                                                        \
    "global_load_dwordx4 %0,  %16, off sc0 sc1\n\t"                    \
    "global_load_dwordx4 %1,  %16, off offset:64 sc0 sc1\n\t"          \
    "global_load_dwordx4 %2,  %16, off offset:128 sc0 sc1\n\t"         \
    "global_load_dwordx4 %3,  %16, off offset:192 sc0 sc1\n\t"         \
    "global_load_dwordx4 %4,  %16, off offset:256 sc0 sc1\n\t"         \
    "global_load_dwordx4 %5,  %16, off offset:320 sc0 sc1\n\t"         \
    "global_load_dwordx4 %6,  %16, off offset:384 sc0 sc1\n\t"         \
    "global_load_dwordx4 %7,  %16, off offset:448 sc0 sc1\n\t"         \
    "global_load_dwordx4 %8,  %16, off offset:512 sc0 sc1\n\t"         \
    "global_load_dwordx4 %9,  %16, off offset:576 sc0 sc1\n\t"         \
    "global_load_dwordx4 %10, %16, off offset:640 sc0 sc1\n\t"         \
    "global_load_dwordx4 %11, %16, off offset:704 sc0 sc1\n\t"         \
    "global_load_dwordx4 %12, %16, off offset:768 sc0 sc1\n\t"         \
    "global_load_dwordx4 %13, %16, off offset:832 sc0 sc1\n\t"         \
    "global_load_dwordx4 %14, %16, off offset:896 sc0 sc1\n\t"         \
    "global_load_dwordx4 %15, %16, off offset:960 sc0 sc1"             \
    : "=&v"(T[0]),  "=&v"(T[1]),  "=&v"(T[2]),  "=&v"(T[3]),           \
      "=&v"(T[4]),  "=&v"(T[5]),  "=&v"(T[6]),  "=&v"(T[7]),           \
      "=&v"(T[8]),  "=&v"(T[9]),  "=&v"(T[10]), "=&v"(T[11]),          \
      "=&v"(T[12]), "=&v"(T[13]), "=&v"(T[14]), "=&v"(T[15])           \
    : "v"(ADDR) : "memory")

// 4 coherent 16B loads, contiguous 64B, acked before return
#define CLOADS4(T, ADDR)                                               \
  asm volatile(                                                        \
    "global_load_dwordx4 %0, %4, off sc0 sc1\n\t"                      \
    "global_load_dwordx4 %1, %4, off offset:16 sc0 sc1\n\t"            \
    "global_load_dwordx4 %2, %4, off offset:32 sc0 sc1\n\t"            \
    "global_load_dwordx4 %3, %4, off offset:48 sc0 sc1\n\t"            \
    "s_waitcnt vmcnt(0)"                                               \
    : "=&v"(T[0]), "=&v"(T[1]), "=&v"(T[2]), "=&v"(T[3])               \
    : "v"(ADDR) : "memory")

// ---------------------------------------------------------------------------
// Kernel 1: Xg[t][b][j] = x_t[b] @ W_ih^T [j] + b_ih[j] + b_hh[j]
// ---------------------------------------------------------------------------
__global__ __launch_bounds__(256) void k_xg(
    const float* __restrict__ img,   // [32][512]
    const int*   __restrict__ gt,    // [32][48]
    const float* __restrict__ emb,   // [32000][512]
    const float* __restrict__ W_ih,  // [2048][512]
    const float* __restrict__ b_ih,
    const float* __restrict__ b_hh,
    float* __restrict__ Xg)          // [48][32][2048]
{
  const int s    = blockIdx.x;
  const int lane = threadIdx.x & 63;
  const int wv   = threadIdx.x >> 6;
  const int nbase = blockIdx.y * 256 + wv * 64;
  const int lr  = lane & 15;
  const int lkb = lane >> 4;

  const float* arow[2];
#pragma unroll
  for (int m = 0; m < 2; ++m) {
    int b = m * 16 + lr;
    const float* src;
    if (s == 0) {
      src = img + b * E_;
    } else {
      int tok = (s == 1) ? 1 : gt[b * T_ + (s - 1)];
      src = emb + (long)tok * E_;
    }
    arow[m] = src;
  }

  f32x4 acc[2][4];
#pragma unroll
  for (int m = 0; m < 2; ++m)
#pragma unroll
    for (int n = 0; n < 4; ++n) acc[m][n] = (f32x4){0.f, 0.f, 0.f, 0.f};

  for (int kt = 0; kt < 16; ++kt) {
    int ko = kt * 32 + lkb * 8;
    bf16x8 a0 = load_cvt8(arow[0] + ko);
    bf16x8 a1 = load_cvt8(arow[1] + ko);
#pragma unroll
    for (int n = 0; n < 4; ++n) {
      const float* wp = W_ih + (long)(nbase + n * 16 + lr) * E_ + ko;
      bf16x8 bw = load_cvt8(wp);
      acc[0][n] = __builtin_amdgcn_mfma_f32_16x16x32_bf16(a0, bw, acc[0][n], 0, 0, 0);
      acc[1][n] = __builtin_amdgcn_mfma_f32_16x16x32_bf16(a1, bw, acc[1][n], 0, 0, 0);
    }
  }

#pragma unroll
  for (int n = 0; n < 4; ++n) {
    int j = nbase + n * 16 + lr;
    float bias = b_ih[j] + b_hh[j];
#pragma unroll
    for (int m = 0; m < 2; ++m) {
#pragma unroll
      for (int r = 0; r < 4; ++r) {
        int b = m * 16 + lkb * 4 + r;
        Xg[((long)(s * B_ + b) * 2048) + j] = acc[m][n][r] + bias;
      }
    }
  }
}

// ---------------------------------------------------------------------------
// Kernel 2 (fused): blocks 0..31 = LSTM recurrence; blocks 32..281 = head GEMM
// consumers that stream logits as steps are published. Producer->consumer data
// (h, hs) moves via sc0/sc1 coherent loads/stores; per-WG progress flags on
// separate cachelines; no RMW atomics, no cache-wide fences.
// Co-residency structural: 282 WGs x 72KB LDS -> 2 WG/CU -> capacity 512.
// ---------------------------------------------------------------------------
__global__ __launch_bounds__(256, 2) void k_fused(
    const float* __restrict__ W_hh,      // [2048][512]
    const float* __restrict__ Xg,        // [48][32][2048]
    const float* __restrict__ W_head,    // [32000][512]
    const float* __restrict__ b_head,    // [32000]
    unsigned short* __restrict__ hbuf,   // [2][32][512] bf16 (double buffer)
    unsigned short* __restrict__ hs,     // [1504][512] bf16
    unsigned* __restrict__ prog,         // [32] progress flags, 128B apart
    float* __restrict__ out)             // [48][32][32000]
{
  __shared__ __align__(16) char lds[73728];   // 72KB: role-carved
  const int tid  = threadIdx.x;
  const int lane = tid & 63;
  const int wv   = tid >> 6;
  const int lr   = lane & 15;
  const int lkb  = lane >> 4;

  if (blockIdx.x < NWG) {
    // ===================== recurrence role =====================
    char* wlds  = lds;            // 64KB W_hh fragments
    char* gbufc = lds + 65536;    // 8KB gate exchange [4][32][16] f32 swizzled
    const int w = blockIdx.x;     // owns hidden dims [16w, 16w+16); wave = gate

    // preload W_hh fragments: gate wv, rows w*16+lr, 16 k-tiles
#pragma unroll
    for (int kt = 0; kt < 16; ++kt) {
      int row = wv * 512 + w * 16 + lr;
      bf16x8 wf = load_cvt8(W_hh + (long)row * E_ + kt * 32 + lkb * 8);
      *(bf16x8*)(wlds + (((wv * 16 + kt) * 64) + lane) * 16) = wf;
    }

    // cell state: thread owns b = tid>>3, dims d0,d0+1 (d0 = (tid&7)*2)
    const int cb_b  = tid >> 3;
    const int cb_d0 = (tid & 7) * 2;
    float c0 = 0.f, c1 = 0.f;

    __syncthreads();

    for (int t = 0; t < T_; ++t) {
      // Xg prefetch (independent of h; overlaps the poll)
      float4 xg[2];
#pragma unroll
      for (int nt = 0; nt < 2; ++nt)
        xg[nt] = *(const float4*)(Xg + ((long)t * B_ + nt * 16 + lr) * 2048 +
                                  wv * 512 + w * 16 + lkb * 4);

      // wait for all WGs to have published step t (h_t stores visible)
      if (t > 0 && wv == 0) {
        const unsigned* pf = prog + (lane & 31) * 32;
        while (true) {
          unsigned v = prog_load(pf);
          if (__ballot(v >= (unsigned)t) == ~0ULL) break;
          __builtin_amdgcn_s_sleep(1);
        }
      }
      __syncthreads();   // releases waves 1..3; also guards gbuf reuse

      // coherent h loads -> B-fragments
      const unsigned short* hcur = hbuf + (t & 1) * (B_ * H_);
      i32x4 tA[16], tB[16];
      const char* aA = (const char*)hcur + (0 * 16 + lr) * 1024 + lkb * 16;
      const char* aB = (const char*)hcur + (1 * 16 + lr) * 1024 + lkb * 16;
      HLOADS16(tA, aA);
      HLOADS16(tB, aB);
      asm volatile("s_waitcnt vmcnt(0)" ::: "memory");
      __builtin_amdgcn_sched_barrier(0);

      f32x4 acc[2];
      acc[0] = (f32x4){0.f, 0.f, 0.f, 0.f};
      acc[1] = (f32x4){0.f, 0.f, 0.f, 0.f};
#pragma unroll
      for (int kt = 0; kt < 16; ++kt) {
        bf16x8 a = *(const bf16x8*)(wlds + (((wv * 16 + kt) * 64) + lane) * 16);
        bf16x8 b0 = *(const bf16x8*)&tA[kt];
        bf16x8 b1 = *(const bf16x8*)&tB[kt];
        acc[0] = __builtin_amdgcn_mfma_f32_16x16x32_bf16(a, b0, acc[0], 0, 0, 0);
        acc[1] = __builtin_amdgcn_mfma_f32_16x16x32_bf16(a, b1, acc[1], 0, 0, 0);
      }

      // exchange: D col = b (lane&15), row = d = lkb*4+reg
      // gbuf row = 64B, block-swizzle ^((b&3)<<4)
#pragma unroll
      for (int nt = 0; nt < 2; ++nt) {
        int b = nt * 16 + lr;
        f32x4 r = acc[nt];
        r[0] += xg[nt].x; r[1] += xg[nt].y; r[2] += xg[nt].z; r[3] += xg[nt].w;
        *(f32x4*)(gbufc + (wv * 32 + b) * 64 + ((lkb * 16) ^ ((b & 3) << 4))) = r;
      }
      __syncthreads();

      // cell update: 2 cells (b = cb_b, d = cb_d0, cb_d0+1)
      int rb = (cb_d0 * 4) ^ ((cb_b & 3) << 4);
      float2 gi  = *(const float2*)(gbufc + (0 * 32 + cb_b) * 64 + rb);
      float2 gf  = *(const float2*)(gbufc + (1 * 32 + cb_b) * 64 + rb);
      float2 gg_ = *(const float2*)(gbufc + (2 * 32 + cb_b) * 64 + rb);
      float2 go  = *(const float2*)(gbufc + (3 * 32 + cb_b) * 64 + rb);

      float cn0 = sigf(gf.x) * c0 + sigf(gi.x) * tanh_fast(gg_.x);
      float cn1 = sigf(gf.y) * c1 + sigf(gi.y) * tanh_fast(gg_.y);
      c0 = cn0; c1 = cn1;
      unsigned short h0 = (unsigned short)f2bf(sigf(go.x) * tanh_fast(cn0));
      unsigned short h1 = (unsigned short)f2bf(sigf(go.y) * tanh_fast(cn1));
      unsigned pk = (unsigned)h0 | ((unsigned)h1 << 16);

      if (t < T_ - 1) {
        unsigned short* hn = hbuf + ((t + 1) & 1) * (B_ * H_) +
                             cb_b * H_ + w * 16 + cb_d0;
        asm volatile("global_store_dword %0, %1, off sc0 sc1"
                     :: "v"(hn), "v"(pk) : "memory");
      }
      if (t >= 1) {
        unsigned short* hp = hs + ((long)(t - 1) * B_ + cb_b) * H_ + w * 16 + cb_d0;
        asm volatile("global_store_dword %0, %1, off sc0 sc1"
                     :: "v"(hp), "v"(pk) : "memory");
      }
      asm volatile("s_waitcnt vmcnt(0)" ::: "memory");

      __syncthreads();               // all threads' stores acked
      if (tid == 0) {
        unsigned val = (unsigned)(t + 1);
        asm volatile("global_store_dword %0, %1, off sc0 sc1"
                     :: "v"(prog + w * 32), "v"(val) : "memory");
      }
    }
  } else {
    // ===================== head-consumer role =====================
    char* stage = lds;                        // 16KB hs m-tile, swizzled
    const int cid = blockIdx.x - NWG;         // 0..249, owns v [cid*128, +128)
    const int vA = cid * 128 + wv * 16 + lr;
    const int vB = vA + 64;

    // W_head fragments in registers (read once; also ramps clocks early)
    bf16x8 bwA[16], bwB[16];
#pragma unroll
    for (int kt = 0; kt < 16; ++kt) {
      bwA[kt] = load_cvt8(W_head + (long)vA * E_ + kt * 32 + lkb * 8);
      bwB[kt] = load_cvt8(W_head + (long)vB * E_ + kt * 32 + lkb * 8);
    }
    float biasA = b_head[vA];
    float biasB = b_head[vB];

    int seen = 0;
    for (int mt = 0; mt < 94; ++mt) {
      int need = mt / 2 + 2;   // hs rows [mt*16, +16) published at prog >= need
      if (seen < need) {
        const unsigned* pf = prog + (lane & 31) * 32;
        while (true) {
          unsigned v = prog_load(pf);
          if (__ballot(v >= (unsigned)need) == ~0ULL) break;
          __builtin_amdgcn_s_sleep(16);
        }
        seen = need;
      }
      __syncthreads();   // all waves gated; also guards stage reuse

      // stage 16 hs rows (16KB) via coherent loads, xor-swizzled LDS
      const char* src = (const char*)(hs + (long)mt * 16 * H_) + tid * 64;
      i32x4 st[4];
      CLOADS4(st, src);
#pragma unroll
      for (int i = 0; i < 4; ++i) {
        int c = tid * 4 + i;
        int row = c >> 6;
        int cb  = (c & 63) * 16;
        *(i32x4*)(stage + row * 1024 + (cb ^ ((row & 7) << 4))) = st[i];
      }
      __syncthreads();

      f32x4 accA = (f32x4){biasA, biasA, biasA, biasA};
      f32x4 accB = (f32x4){biasB, biasB, biasB, biasB};
#pragma unroll
      for (int kt = 0; kt < 16; ++kt) {
        int cb = kt * 64 + lkb * 16;
        i32x4 av = *(const i32x4*)(stage + lr * 1024 + (cb ^ ((lr & 7) << 4)));
        bf16x8 a = *(bf16x8*)&av;
        accA = __builtin_amdgcn_mfma_f32_16x16x32_bf16(a, bwA[kt], accA, 0, 0, 0);
        accB = __builtin_amdgcn_mfma_f32_16x16x32_bf16(a, bwB[kt], accB, 0, 0, 0);
      }

#pragma unroll
      for (int r = 0; r < 4; ++r) {
        int R = mt * 16 + lkb * 4 + r;          // hs row; out row = R + 32
        out[(long)(R + 32) * V_ + vA] = accA[r];
        out[(long)(R + 32) * V_ + vB] = accB[r];
      }
    }
  }
}

// ---------------------------------------------------------------------------
extern "C" void kernel_launch(void* const* d_in, const int* in_sizes, int n_in,
                              void* d_out, int out_size, void* d_ws, size_t ws_size,
                              hipStream_t stream) {
  const float* img  = (const float*)d_in[0];
  const int*   gt   = (const int*)d_in[1];
  const float* emb  = (const float*)d_in[2];
  const float* W_ih = (const float*)d_in[3];
  const float* W_hh = (const float*)d_in[4];
  const float* b_ih = (const float*)d_in[5];
  const float* b_hh = (const float*)d_in[6];
  const float* W_hd = (const float*)d_in[7];
  const float* b_hd = (const float*)d_in[8];
  float* out = (float*)d_out;

  char* ws = (char*)d_ws;
  unsigned*       prog = (unsigned*)(ws);                           // 4096 B (32 x 128B)
  unsigned short* hbuf = (unsigned short*)(ws + 4096);              // 65536 B
  unsigned short* hs   = (unsigned short*)(ws + 4096 + 65536);      // 1540096 B
  float*          Xg   = (float*)(ws + 4096 + 65536 + 1540096);     // 12582912 B

  hipMemsetAsync(prog, 0, 4096, stream);
  hipMemsetAsync(hbuf, 0, B_ * H_ * sizeof(unsigned short), stream);  // h_0 = 0
  hipMemsetAsync(out, 0, (size_t)B_ * V_ * sizeof(float), stream);    // outputs[0] = 0

  dim3 g1(48, 8);
  k_xg<<<g1, 256, 0, stream>>>(img, gt, emb, W_ih, b_ih, b_hh, Xg);
  k_fused<<<GRID, 256, 0, stream>>>(W_hh, Xg, W_hd, b_hd, hbuf, hs, prog, out);
}